// Round 17
// baseline (37.641 us; speedup 1.0000x reference)
//
#include <hip/hip_runtime.h>
#include <hip/hip_fp16.h>

typedef __attribute__((ext_vector_type(4))) float f32x4;

#define NROWS 8192
#define DCOLS 256
#define MARGIN 0.5f
#define NT 64          // 8192/128 tiles per dim
#define NBLOCKS 544    // sum over rows bi of ceil((64-bi)/4) runs of <=4 j-tiles

// --- Kernel 1: L2-normalize rows fp32 -> fp8 e5m2 (= truncated fp16), row-major.
// Also zeroes the global accumulator + completion counter (replay-safe).
__global__ __launch_bounds__(256) void norm_kernel(const float* __restrict__ x,
                                                   unsigned char* __restrict__ e,
                                                   float* __restrict__ acc,
                                                   unsigned int* __restrict__ cnt) {
    if (blockIdx.x == 0 && threadIdx.x == 0) { acc[0] = 0.0f; cnt[0] = 0u; }
    const int t = threadIdx.x;
    const int l = t & 63;
    const int c = l & 31;
    const int row = blockIdx.x * 8 + (t >> 6) * 2 + (l >> 5);

    const float4 v0 = *reinterpret_cast<const float4*>(&x[row * DCOLS + c * 8]);
    const float4 v1 = *reinterpret_cast<const float4*>(&x[row * DCOLS + c * 8 + 4]);
    float ss = v0.x * v0.x + v0.y * v0.y + v0.z * v0.z + v0.w * v0.w
             + v1.x * v1.x + v1.y * v1.y + v1.z * v1.z + v1.w * v1.w;
#pragma unroll
    for (int off = 16; off >= 1; off >>= 1) ss += __shfl_xor(ss, off, 32);
    const float inv = 1.0f / fmaxf(sqrtf(ss), 1e-12f);

    const float f[8] = {v0.x, v0.y, v0.z, v0.w, v1.x, v1.y, v1.z, v1.w};
    unsigned int lo = 0, hi = 0;
#pragma unroll
    for (int i = 0; i < 4; ++i) {
        const unsigned short hb = __half_as_ushort(__float2half(f[i] * inv));
        lo |= (unsigned int)(hb >> 8) << (8 * i);           // e5m2 = fp16 top byte
    }
#pragma unroll
    for (int i = 0; i < 4; ++i) {
        const unsigned short hb = __half_as_ushort(__float2half(f[4 + i] * inv));
        hi |= (unsigned int)(hb >> 8) << (8 * i);
    }
    uint2 o; o.x = lo; o.y = hi;
    *reinterpret_cast<uint2*>(e + (size_t)row * DCOLS + c * 8) = o;
}

// --- Kernel 2: R16 barrier-free wave-private pipeline, NO setprio (R17), with
// fused finalize (last-block-done). Block = (bi, run of <=4 j-tiles), 256 thr
// = 4 free-drifting waves. Tile 128x128; wave owns cols wn*32 (acc[8][2] of
// 16x16x32 bf8_bf8). A (128xK=256 fp8) in LDS (conflict-free k-major layout);
// B: wave-private 1 KB ring-4 slices, own-vmcnt ordered, no in-loop barriers.
// Step s prefetches step s+1's fragments into parity regs before its MFMAs.
__global__ __launch_bounds__(256, 3) void tile_kernel(const unsigned char* __restrict__ e,
                                                      float* __restrict__ acc,
                                                      unsigned int* __restrict__ cnt,
                                                      float* __restrict__ out) {
    // XCD-chunked bijective remap (544 = 8*68)
    const int orig = blockIdx.x;
    int bb = (orig & 7) * 68 + (orig >> 3);
    int bi = 0;
    while (bb >= ((NT - bi) + 3) >> 2) { bb -= ((NT - bi) + 3) >> 2; ++bi; }
    const int j0 = bi + bb * 4;
    const int nj = min(4, NT - j0);
    const int NS = nj * 8;                    // stream of (jt,kt) steps

    __shared__ char As[32768];                // [kt 0..7][khalf 0..1][row 0..127][16B]
    __shared__ char Bw[4][4][1024];           // [wave][slot][khalf 0..1][row 0..31][16B]
    __shared__ float red[4];

    const int t = threadIdx.x;
    const int l = t & 63;
    const int w = t >> 6;       // wave id = N-slice: cols wn*32
    const int wn = w;
    const int lr = l & 15;
    const int hk = l >> 4;
    const unsigned char* eA = e + (size_t)bi * 128 * DCOLS;
    const unsigned char* eB = e + (size_t)j0 * 128 * DCOLS + wn * 32 * DCOLS;
    char* myB = Bw[w][0];

    // --- prologue: stage A (8 loads/thread), B streams 0..2 -> slots 0..2 ---
#pragma unroll
    for (int i = 0; i < 8; ++i) {
        const int u = i * 256 + t;            // kt*256 + khalf*128 + row
        const int kt = u >> 8, khalf = (u >> 7) & 1, row = u & 127;
        __builtin_amdgcn_global_load_lds(
            (const __attribute__((address_space(1))) void*)(eA + row * DCOLS + kt * 32 + khalf * 16),
            (__attribute__((address_space(3))) void*)(As + u * 16), 16, 0, 0);
    }
#pragma unroll
    for (int p = 0; p < 3; ++p) {
        __builtin_amdgcn_global_load_lds(
            (const __attribute__((address_space(1))) void*)(eB + (l & 31) * DCOLS + p * 32 + (l >> 5) * 16),
            (__attribute__((address_space(3))) void*)(myB + p * 1024 + l * 16), 16, 0, 0);
    }
    asm volatile("s_waitcnt vmcnt(3)" ::: "memory");   // A landed; 3 B in flight
    __builtin_amdgcn_s_barrier();             // the ONLY barrier: publishes A
    __builtin_amdgcn_sched_barrier(0);

    const int rd_base = (hk >> 1) ? 1 : 0;    // khalf of this lane's k-offset
    const int aoff = rd_base * 2048 + lr * 16 + (hk & 1) * 8;   // + m*256 + kt*4096
    const int boff = rd_base * 512 + lr * 16 + (hk & 1) * 8;    // + n*256 + slot*1024

    f32x4 acc_r[8][2];
#pragma unroll
    for (int m = 0; m < 8; ++m)
#pragma unroll
        for (int n = 0; n < 2; ++n)
            acc_r[m][n] = (f32x4){0.f, 0.f, 0.f, 0.f};

    // parity-double-buffered fragment registers (static indices, rule #20)
    long afb[2][8], bfb[2][2];
    asm volatile("s_waitcnt vmcnt(2)" ::: "memory");   // slot 0 landed
#pragma unroll
    for (int m = 0; m < 8; ++m)
        afb[0][m] = *reinterpret_cast<const long*>(As + 0 * 4096 + m * 256 + aoff);
#pragma unroll
    for (int n = 0; n < 2; ++n)
        bfb[0][n] = *reinterpret_cast<const long*>(myB + 0 * 1024 + n * 256 + boff);

    float local = 0.0f;
    for (int jx = 0; jx < nj; ++jx) {
        const int jt = j0 + jx;
#pragma unroll
        for (int kt = 0; kt < 8; ++kt) {
            const int s = jx * 8 + kt;
            const int cur = kt & 1, nxt = cur ^ 1;
            // issue stage for stream s+3 into slot (kt+3)&3 (outstanding -> 3)
            {
                int s3 = s + 3; if (s3 >= NS) s3 -= NS;   // wrap: identical bytes
                __builtin_amdgcn_global_load_lds(
                    (const __attribute__((address_space(1))) void*)(eB
                        + (size_t)(s3 >> 3) * 128 * DCOLS
                        + (l & 31) * DCOLS + (s3 & 7) * 32 + (l >> 5) * 16),
                    (__attribute__((address_space(3))) void*)(myB + ((kt + 3) & 3) * 1024 + l * 16),
                    16, 0, 0);
            }
            // prefetch step s+1's fragments (latency hides under this step's MFMAs)
            const bool have_next = (kt < 7) || (jx + 1 < nj);
            if (have_next) {
                asm volatile("s_waitcnt vmcnt(2)" ::: "memory");   // stream s+1 landed
#pragma unroll
                for (int n = 0; n < 2; ++n)
                    bfb[nxt][n] = *reinterpret_cast<const long*>(
                        myB + ((kt + 1) & 3) * 1024 + n * 256 + boff);
#pragma unroll
                for (int m = 0; m < 8; ++m)
                    afb[nxt][m] = *reinterpret_cast<const long*>(
                        As + ((kt + 1) & 7) * 4096 + m * 256 + aoff);
            }
#pragma unroll
            for (int m = 0; m < 8; ++m)
#pragma unroll
                for (int n = 0; n < 2; ++n)
                    acc_r[m][n] = __builtin_amdgcn_mfma_f32_16x16x32_bf8_bf8(
                        afb[cur][m], bfb[cur][n], acc_r[m][n], 0, 0, 0);
        }
        // --- tile jt complete: fused masked-relu reduce, reset acc ---
        // C/D layout (m89-verified, dtype-independent): col=lane&15,
        // row=(lane>>4)*4+reg.
        const int gi0 = bi * 128;
        const int gj0 = jt * 128 + wn * 32;
        if (jt == bi) {
#pragma unroll
            for (int m = 0; m < 8; ++m)
#pragma unroll
                for (int n = 0; n < 2; ++n) {
#pragma unroll
                    for (int r = 0; r < 4; ++r) {
                        const int gi = gi0 + m * 16 + hk * 4 + r;
                        const int gj = gj0 + n * 16 + lr;
                        local += (gi < gj) ? fmaxf(acc_r[m][n][r] - MARGIN, 0.0f) : 0.0f;
                    }
                    acc_r[m][n] = (f32x4){0.f, 0.f, 0.f, 0.f};
                }
        } else {   // jt > bi: all pairs strictly upper-triangular
#pragma unroll
            for (int m = 0; m < 8; ++m)
#pragma unroll
                for (int n = 0; n < 2; ++n) {
#pragma unroll
                    for (int r = 0; r < 4; ++r)
                        local += fmaxf(acc_r[m][n][r] - MARGIN, 0.0f);
                    acc_r[m][n] = (f32x4){0.f, 0.f, 0.f, 0.f};
                }
        }
    }

    // --- block reduction -> one atomic add; last block finalizes out ---
#pragma unroll
    for (int off = 32; off >= 1; off >>= 1) local += __shfl_down(local, off);
    if (l == 0) red[w] = local;
    __syncthreads();
    if (t == 0) {
        atomicAdd(acc, red[0] + red[1] + red[2] + red[3]);
        __threadfence();
        const unsigned int old = atomicAdd(cnt, 1u);
        if (old == NBLOCKS - 1) {             // last block: all adds visible
            __threadfence();
            const float s = atomicAdd(acc, 0.0f);   // coherent read
            out[0] = s / 33550336.0f;         // n*(n-1)/2 for n=8192
        }
    }
}

extern "C" void kernel_launch(void* const* d_in, const int* in_sizes, int n_in,
                              void* d_out, int out_size, void* d_ws, size_t ws_size,
                              hipStream_t stream) {
    const float* x = (const float*)d_in[0];
    float* out = (float*)d_out;
    unsigned char* e = (unsigned char*)d_ws;                            // 2 MB fp8
    float* acc = (float*)((char*)d_ws + (size_t)NROWS * DCOLS);         // 1 float
    unsigned int* cnt = (unsigned int*)((char*)d_ws + (size_t)NROWS * DCOLS + 64);

    norm_kernel<<<NROWS / 8, 256, 0, stream>>>(x, e, acc, cnt);
    tile_kernel<<<NBLOCKS, 256, 0, stream>>>(e, acc, cnt, out);
}

// Round 18
// 30.843 us; speedup vs baseline: 1.2204x; 1.2204x over previous
//
#include <hip/hip_runtime.h>
#include <hip/hip_fp16.h>

typedef __attribute__((ext_vector_type(4))) float f32x4;
typedef __attribute__((ext_vector_type(8))) int i32x8;

#define NROWS 8192
#define DCOLS 256
#define MARGIN 0.5f
#define NT 64          // 8192/128 tiles per dim
#define NBLOCKS 544    // sum over rows bi of ceil((64-bi)/4) runs of <=4 j-tiles

// --- Kernel 1: L2-normalize rows fp32 -> fp8 e5m2 (= truncated fp16), row-major.
__global__ __launch_bounds__(256) void norm_kernel(const float* __restrict__ x,
                                                   unsigned char* __restrict__ e) {
    const int t = threadIdx.x;
    const int l = t & 63;
    const int c = l & 31;
    const int row = blockIdx.x * 8 + (t >> 6) * 2 + (l >> 5);

    const float4 v0 = *reinterpret_cast<const float4*>(&x[row * DCOLS + c * 8]);
    const float4 v1 = *reinterpret_cast<const float4*>(&x[row * DCOLS + c * 8 + 4]);
    float ss = v0.x * v0.x + v0.y * v0.y + v0.z * v0.z + v0.w * v0.w
             + v1.x * v1.x + v1.y * v1.y + v1.z * v1.z + v1.w * v1.w;
#pragma unroll
    for (int off = 16; off >= 1; off >>= 1) ss += __shfl_xor(ss, off, 32);
    const float inv = 1.0f / fmaxf(sqrtf(ss), 1e-12f);

    const float f[8] = {v0.x, v0.y, v0.z, v0.w, v1.x, v1.y, v1.z, v1.w};
    unsigned int lo = 0, hi = 0;
#pragma unroll
    for (int i = 0; i < 4; ++i) {
        const unsigned short hb = __half_as_ushort(__float2half(f[i] * inv));
        lo |= (unsigned int)(hb >> 8) << (8 * i);           // e5m2 = fp16 top byte
    }
#pragma unroll
    for (int i = 0; i < 4; ++i) {
        const unsigned short hb = __half_as_ushort(__float2half(f[4 + i] * inv));
        hi |= (unsigned int)(hb >> 8) << (8 * i);
    }
    uint2 o; o.x = lo; o.y = hi;
    *reinterpret_cast<uint2*>(e + (size_t)row * DCOLS + c * 8) = o;
}

// --- Kernel 2: MX-fp8 K=128 MFMA + A-in-registers + barrier-free wave-private
// B pipeline (R18). Block = (bi, run of <=4 j-tiles), 256 thr = 4 free waves.
// Tile 128x128; wave owns cols wn*32: acc[8][2] of mfma_scale_f32_16x16x128
// (bf8/bf8, scale=1.0). K=256 -> 2 K128-steps/tile. A panel hoisted to
// af[2][8] regs (128 VGPR) via a 16KB LDS bounce (2 rounds) -> in-loop LDS
// reads are B-only (2x i32x8/step). B: wave-private 4KB ring-3, own-vmcnt
// counted gating (vmcnt(4)), no in-loop barriers.
// LDS layout (A round): [hk][row128][32B]; (B slot): [hk][row32][32B]; lane
// (lr,hk) reads 32B contiguous at hk*R*32 + row*32 (b128 pair).
__global__ __launch_bounds__(256, 2) void tile_kernel(const unsigned char* __restrict__ e,
                                                      float* __restrict__ part) {
    // XCD-chunked bijective remap (544 = 8*68)
    const int orig = blockIdx.x;
    int bb = (orig & 7) * 68 + (orig >> 3);
    int bi = 0;
    while (bb >= ((NT - bi) + 3) >> 2) { bb -= ((NT - bi) + 3) >> 2; ++bi; }
    const int j0 = bi + bb * 4;
    const int nj = min(4, NT - j0);
    const int NS = nj * 2;                    // K128-steps

    __shared__ char lds[65536];               // [0,16K): A bounce ; [16K,64K): Bw
    char* As = lds;                           // 16KB: [hk][row128][32B]
    char* Bw = lds + 16384;                   // 4 waves x 3 slots x 4KB
    float* red = (float*)lds;                 // reuse dead A region at the end

    const int t = threadIdx.x;
    const int l = t & 63;
    const int w = t >> 6;       // wave id = N-slice: cols wn*32
    const int wn = w;
    const int lr = l & 15;
    const int hk = l >> 4;
    const unsigned char* eA = e + (size_t)bi * 128 * DCOLS;
    const unsigned char* eB = e + (size_t)j0 * 128 * DCOLS + wn * 32 * DCOLS;
    char* myB = Bw + w * 12288;

    // stage one B K128-panel (stream s: tile j0+(s>>1), kblock s&1) into a slot.
    // chunk u = i*64 + l: hk=(u>>6)&3, row=(u>>1)&31, c=u&1; 4 loads/lane.
    auto stageB = [&](int stream, int slot) {
#pragma unroll
        for (int i = 0; i < 4; ++i) {
            const int u = i * 64 + l;
            const int shk = (u >> 6) & 3, srow = (u >> 1) & 31, sc = u & 1;
            __builtin_amdgcn_global_load_lds(
                (const __attribute__((address_space(1))) void*)(eB
                    + (size_t)(stream >> 1) * 128 * DCOLS
                    + srow * DCOLS + (stream & 1) * 128 + shk * 32 + sc * 16),
                (__attribute__((address_space(3))) void*)(myB + slot * 4096 + u * 16),
                16, 0, 0);
        }
    };

    // --- prologue ---
    // A round 0 (kblock 0): 4 loads/thread. chunk u = i*256+t: hk=(u>>8)&3,
    // row=(u>>1)&127, c=u&1.
#pragma unroll
    for (int i = 0; i < 4; ++i) {
        const int u = i * 256 + t;
        const int shk = (u >> 8) & 3, srow = (u >> 1) & 127, sc = u & 1;
        __builtin_amdgcn_global_load_lds(
            (const __attribute__((address_space(1))) void*)(eA + srow * DCOLS + shk * 32 + sc * 16),
            (__attribute__((address_space(3))) void*)(As + u * 16), 16, 0, 0);
    }
    stageB(0, 0);
    stageB(1, 1);
    asm volatile("s_waitcnt vmcnt(8)" ::: "memory");   // A0 landed; 8 B in flight
    __builtin_amdgcn_s_barrier();
    __builtin_amdgcn_sched_barrier(0);

    i32x8 af[2][8];
#pragma unroll
    for (int m = 0; m < 8; ++m)
        af[0][m] = *reinterpret_cast<const i32x8*>(As + hk * 4096 + (m * 16 + lr) * 32);
    __builtin_amdgcn_s_barrier();             // all waves done reading A0
    __builtin_amdgcn_sched_barrier(0);
    // A round 1 (kblock 1) into the same 16KB
#pragma unroll
    for (int i = 0; i < 4; ++i) {
        const int u = i * 256 + t;
        const int shk = (u >> 8) & 3, srow = (u >> 1) & 127, sc = u & 1;
        __builtin_amdgcn_global_load_lds(
            (const __attribute__((address_space(1))) void*)(eA + srow * DCOLS + 128 + shk * 32 + sc * 16),
            (__attribute__((address_space(3))) void*)(As + u * 16), 16, 0, 0);
    }
    asm volatile("s_waitcnt vmcnt(0)" ::: "memory");   // drain (prologue-only)
    __builtin_amdgcn_s_barrier();
    __builtin_amdgcn_sched_barrier(0);
#pragma unroll
    for (int m = 0; m < 8; ++m)
        af[1][m] = *reinterpret_cast<const i32x8*>(As + hk * 4096 + (m * 16 + lr) * 32);
    // As now dead (red[] reuses it after the loop). B streams 0,1 landed.

    f32x4 acc[8][2];
#pragma unroll
    for (int m = 0; m < 8; ++m)
#pragma unroll
        for (int n = 0; n < 2; ++n)
            acc[m][n] = (f32x4){0.f, 0.f, 0.f, 0.f};

    float local = 0.0f;
    for (int jx = 0; jx < nj; ++jx) {
        const int jt = j0 + jx;
#pragma unroll
        for (int kb = 0; kb < 2; ++kb) {
            const int s = jx * 2 + kb;
            // own oldest B stage has landed (counted; trivially true for s<2)
            asm volatile("s_waitcnt vmcnt(4)" ::: "memory");
            // stage stream s+2 into slot (s+2)%3 (wrap: identical bytes, benign)
            {
                int s2 = s + 2; if (s2 >= NS) s2 -= NS;
                int slot = s + 2; while (slot >= 3) slot -= 3;
                stageB(s2, slot);
            }
            int slotc = s; while (slotc >= 3) slotc -= 3;
            i32x8 bf[2];
#pragma unroll
            for (int n = 0; n < 2; ++n)
                bf[n] = *reinterpret_cast<const i32x8*>(
                    myB + slotc * 4096 + hk * 1024 + (n * 16 + lr) * 32);
            __builtin_amdgcn_s_setprio(1);
#pragma unroll
            for (int m = 0; m < 8; ++m)
#pragma unroll
                for (int n = 0; n < 2; ++n)
                    acc[m][n] = __builtin_amdgcn_mfma_scale_f32_16x16x128_f8f6f4(
                        af[kb][m], bf[n], acc[m][n],
                        1, 1,                     // cbsz=BF8(e5m2), blgp=BF8
                        0, 0x7F7F7F7F,            // scale A = 1.0
                        0, 0x7F7F7F7F);           // scale B = 1.0
            __builtin_amdgcn_s_setprio(0);
        }
        // --- tile jt complete: fused masked-relu reduce, reset acc ---
        // C/D layout (m89-verified; shape-determined for f8f6f4): col=lane&15,
        // row=(lane>>4)*4+reg.
        const int gi0 = bi * 128;
        const int gj0 = jt * 128 + wn * 32;
        if (jt == bi) {
#pragma unroll
            for (int m = 0; m < 8; ++m)
#pragma unroll
                for (int n = 0; n < 2; ++n) {
#pragma unroll
                    for (int r = 0; r < 4; ++r) {
                        const int gi = gi0 + m * 16 + hk * 4 + r;
                        const int gj = gj0 + n * 16 + lr;
                        local += (gi < gj) ? fmaxf(acc[m][n][r] - MARGIN, 0.0f) : 0.0f;
                    }
                    acc[m][n] = (f32x4){0.f, 0.f, 0.f, 0.f};
                }
        } else {   // jt > bi: all pairs strictly upper-triangular
#pragma unroll
            for (int m = 0; m < 8; ++m)
#pragma unroll
                for (int n = 0; n < 2; ++n) {
#pragma unroll
                    for (int r = 0; r < 4; ++r)
                        local += fmaxf(acc[m][n][r] - MARGIN, 0.0f);
                    acc[m][n] = (f32x4){0.f, 0.f, 0.f, 0.f};
                }
        }
    }

    // --- block reduction -> one partial per block, no atomics ---
#pragma unroll
    for (int off = 32; off >= 1; off >>= 1) local += __shfl_down(local, off);
    __syncthreads();                          // all loop-LDS traffic done
    if (l == 0) red[w] = local;
    __syncthreads();
    if (t == 0) part[orig] = red[0] + red[1] + red[2] + red[3];
}

// --- Kernel 3: reduce NBLOCKS partials, finalize ---
__global__ __launch_bounds__(256) void fin_kernel(const float* __restrict__ part,
                                                  float* __restrict__ out) {
    __shared__ float red[4];
    const int t = threadIdx.x;
    float v = part[t] + part[t + 256] + (t < NBLOCKS - 512 ? part[t + 512] : 0.0f);
#pragma unroll
    for (int off = 32; off >= 1; off >>= 1) v += __shfl_down(v, off);
    if ((t & 63) == 0) red[t >> 6] = v;
    __syncthreads();
    if (t == 0) out[0] = (red[0] + red[1] + red[2] + red[3]) / 33550336.0f;
}

extern "C" void kernel_launch(void* const* d_in, const int* in_sizes, int n_in,
                              void* d_out, int out_size, void* d_ws, size_t ws_size,
                              hipStream_t stream) {
    const float* x = (const float*)d_in[0];
    float* out = (float*)d_out;
    unsigned char* e = (unsigned char*)d_ws;                        // 2 MB fp8
    float* part = (float*)((char*)d_ws + (size_t)NROWS * DCOLS);    // 544 floats

    norm_kernel<<<NROWS / 8, 256, 0, stream>>>(x, e);
    tile_kernel<<<NBLOCKS, 256, 0, stream>>>(e, part);
    fin_kernel<<<1, 256, 0, stream>>>(part, out);
}